// Round 1
// 407.254 us; speedup vs baseline: 1.0720x; 1.0720x over previous
//
#include <hip/hip_runtime.h>

typedef _Float16 half8_t __attribute__((ext_vector_type(8)));
typedef float f32x4 __attribute__((ext_vector_type(4)));

#define B_ 128
#define N_ 4096
#define H_ 128
#define P_ 128
#define CCH 8                        // chunks per batch row -> 1024 blocks = 4/CU exactly
#define ROWS_PER_CHUNK (N_ / CCH)    // 512
#define TILES (ROWS_PER_CHUNK / 64)  // 8 iterations of 64 rows (16/wave)

// workspace layout (float offsets)
#define OFF_SCALES 0          // [0]=sv [1]=sq [2]=sa
#define OFF_WA     16         // 128 floats: normalized wa
#define OFF_BPACK  16640      // 16384 f16 = 8192 float slots: MFMA-packed Wv^T
#define OFF_LOGITS 24832      // B*N floats
#define OFF_PART   549120     // B*CCH*132 floats: per-(b,chunk) m,l,o[128],pad2

// ---------- K0: norms, scales, normalized wa, MFMA-packed Wv ----------
// R6: 1024 threads (was 256) + wave-shuffle reductions (was 24-barrier LDS
// ladder). Single block is unavoidable (global norm), so maximize its ILP.
__global__ __launch_bounds__(1024) void k0_prep(
    const float* __restrict__ Wv, const float* __restrict__ gv,
    const float* __restrict__ Wq, const float* __restrict__ gq,
    const float* __restrict__ Wa, const float* __restrict__ ga,
    float* __restrict__ ws)
{
    const int tid  = threadIdx.x;
    const int lane = tid & 63;
    const int w    = tid >> 6;          // 16 waves

    float sv2 = 0.f, sq2 = 0.f, sa2 = 0.f;
    const float4* Wv4 = (const float4*)Wv;
    const float4* Wq4 = (const float4*)Wq;
#pragma unroll
    for (int i = 0; i < 4; ++i) {       // 4096 float4 total / 1024 threads
        float4 a = Wv4[tid + i * 1024];
        sv2 += a.x * a.x + a.y * a.y + a.z * a.z + a.w * a.w;
        float4 b = Wq4[tid + i * 1024];
        sq2 += b.x * b.x + b.y * b.y + b.z * b.z + b.w * b.w;
    }
    if (tid < P_) { float z = Wa[tid]; sa2 = z * z; }

#pragma unroll
    for (int m = 1; m <= 32; m <<= 1) {
        sv2 += __shfl_xor(sv2, m, 64);
        sq2 += __shfl_xor(sq2, m, 64);
        sa2 += __shfl_xor(sa2, m, 64);
    }
    __shared__ float rv[16], rq[16], ra[16];
    __shared__ float s_sv, s_sa;
    if (lane == 0) { rv[w] = sv2; rq[w] = sq2; ra[w] = sa2; }
    __syncthreads();
    if (tid == 0) {
        float nv = 0.f, nq = 0.f, na = 0.f;
#pragma unroll
        for (int i = 0; i < 16; ++i) { nv += rv[i]; nq += rq[i]; na += ra[i]; }
        float sv = gv[0] / sqrtf(nv);
        float sq = gq[0] / sqrtf(nq);
        float sa = ga[0] / sqrtf(na);
        ws[OFF_SCALES + 0] = sv;
        ws[OFF_SCALES + 1] = sq;
        ws[OFF_SCALES + 2] = sa;
        s_sv = sv; s_sa = sa;
    }
    __syncthreads();

    const float sv = s_sv, sa = s_sa;
    // Bpack[s]: s = ((kk*8+pt)*64 + L)*8 + j  ->  Wv[p][h]*sv with
    // p = pt*16 + (L&15), h = kk*32 + (L>>4)*8 + j   (MFMA B-fragment order)
    _Float16* bp = (_Float16*)(ws + OFF_BPACK);
#pragma unroll
    for (int k = 0; k < 16; ++k) {      // 16384 / 1024
        int s  = tid + k * 1024;
        int j  = s & 7;
        int L  = (s >> 3) & 63;
        int pt = (s >> 9) & 7;
        int kk = s >> 12;
        int p = pt * 16 + (L & 15);
        int h = kk * 32 + (L >> 4) * 8 + j;
        bp[s] = (_Float16)(Wv[p * H_ + h] * sv);
    }
    if (tid < P_) ws[OFF_WA + tid] = Wa[tid] * sa;
}

// ---------- K1: one pass over v; wave-private online softmax, zero barriers
// in the K-loop. v is read from HBM EXACTLY ONCE — the o-update converts
// the f16 A-fragments back to f32 (32 v_cvt, no memory) instead of reloading.
// CCH=8 -> 1024 blocks = exactly 4 blocks/CU (LDS cap): single co-resident
// batch, 8 iters amortize the 32 KB B-stage prologue.
// R6: qpc[b][:] computed inline per block (Wq is L2-hot across 1024 blocks;
// 16K MACs hide under the Bl staging loads) — removes the k0b launch.
__global__ __launch_bounds__(256) void k1_main(
    const float* __restrict__ v, const float* __restrict__ mask,
    const float* __restrict__ ba,
    const float* __restrict__ q, const float* __restrict__ Wq,
    const float* __restrict__ bq, const float* __restrict__ bv,
    float* __restrict__ ws)
{
    const int c = blockIdx.x;   // chunk
    const int b = blockIdx.y;   // batch
    const int tid = threadIdx.x;
    const int lane = tid & 63;
    const int w = tid >> 6;     // wave id 0..3

    __shared__ __align__(16) _Float16 Bl[16384];   // 32 KB packed B-frags
    __shared__ float qpcs[P_];
    __shared__ float was[P_];
    __shared__ float smask[ROWS_PER_CHUNK];        // 2 KB chunk mask
    __shared__ float obuf[4][P_];                  // per-wave o partials
    __shared__ float mbuf[4], lbuf[4];

    {
        // stage packed B (loads issue first; qproj MACs below overlap them)
        const uint4* src = (const uint4*)(ws + OFF_BPACK);
        uint4* dst = (uint4*)Bl;
#pragma unroll
        for (int i = 0; i < 8; ++i) dst[tid + i * 256] = src[tid + i * 256];

        // inline q_proj: 2 threads per p, 64 MACs each (float4)
        const int p  = tid >> 1;
        const int hh = tid & 1;
        const float sq = ws[OFF_SCALES + 1];
        const float4* qr = (const float4*)(q + (size_t)b * H_) + hh * 16;
        const float4* wr = (const float4*)(Wq + (size_t)p * H_) + hh * 16;
        float acc = 0.f;
#pragma unroll
        for (int i = 0; i < 16; ++i) {
            float4 a = qr[i], cc4 = wr[i];
            acc += a.x * cc4.x + a.y * cc4.y + a.z * cc4.z + a.w * cc4.w;
        }
        acc += __shfl_xor(acc, 1, 64);
        if (hh == 0) qpcs[p] = acc * sq + bq[p] + bv[p];

        if (tid < P_) was[tid] = ws[OFF_WA + tid];
#pragma unroll
        for (int i = 0; i < ROWS_PER_CHUNK / 256; ++i)
            smask[tid + i * 256] = mask[(size_t)b * N_ + c * ROWS_PER_CHUNK + tid + i * 256];
    }
    const float ba0 = ba[0];
    __syncthreads();

    const int rloc = lane & 15;        // v-row owned by this lane (A-frag m)
    const int grp  = lane >> 4;        // 16-lane group id 0..3
    const int colb = grp * 8;          // col sub-block within each 32-col slice

    float m_w = -1e30f, l_w = 0.f;
    float o32[32];
#pragma unroll
    for (int j = 0; j < 32; ++j) o32[j] = 0.f;

    for (int it = 0; it < TILES; ++it) {
        const int r0 = it * 64 + w * 16;                 // row offset in chunk
        const int n0w = c * ROWS_PER_CHUNK + r0;         // global row

        // ---- load 16x128 tile -> f16 A-frags (sole HBM touch of v)
        const float* vrow = v + ((size_t)b * N_ + n0w + rloc) * H_;
        half8_t af[4];
#pragma unroll
        for (int kk = 0; kk < 4; ++kk) {
            const float4* p4 = (const float4*)(vrow + kk * 32 + colb);
            float4 f0 = p4[0], f1 = p4[1];
            half8_t a;
            a[0] = (_Float16)f0.x; a[1] = (_Float16)f0.y;
            a[2] = (_Float16)f0.z; a[3] = (_Float16)f0.w;
            a[4] = (_Float16)f1.x; a[5] = (_Float16)f1.y;
            a[6] = (_Float16)f1.z; a[7] = (_Float16)f1.w;
            af[kk] = a;
        }

        // ---- v_proj via MFMA + relu·wa partial logits
        float lp[4];
        lp[0] = lp[1] = lp[2] = lp[3] = 0.f;
#pragma unroll
        for (int pt = 0; pt < 8; ++pt) {
            const int p = pt * 16 + rloc;
            const float qv = qpcs[p];
            f32x4 acc = {qv, qv, qv, qv};      // fold q_proj into C init
#pragma unroll
            for (int kk = 0; kk < 4; ++kk) {
                half8_t bf = *(const half8_t*)&Bl[(((kk * 8 + pt) * 64) + lane) * 8];
                acc = __builtin_amdgcn_mfma_f32_16x16x32_f16(af[kk], bf, acc, 0, 0, 0);
            }
            const float wv = was[p];
#pragma unroll
            for (int r = 0; r < 4; ++r)
                lp[r] += fmaxf(acc[r], 0.f) * wv;
        }
        // reduce over the 16 p-cols (lanes differing in bits 0-3)
#pragma unroll
        for (int m = 1; m <= 8; m <<= 1) {
#pragma unroll
            for (int r = 0; r < 4; ++r) lp[r] += __shfl_xor(lp[r], m, 64);
        }
        // lp[r] is now the logit of row (grp*4 + r); add bias + mask (LDS)
#pragma unroll
        for (int r = 0; r < 4; ++r) {
            const float mk = smask[r0 + grp * 4 + r];
            lp[r] += ba0 + (1.0f - mk) * (-10000.0f);
        }

        // transpose: lg_me = logit of row rloc (the row this lane HOLDS)
        const int srcl = (rloc >> 2) << 4;
        float t0 = __shfl(lp[0], srcl, 64);
        float t1 = __shfl(lp[1], srcl, 64);
        float t2 = __shfl(lp[2], srcl, 64);
        float t3 = __shfl(lp[3], srcl, 64);
        float a01 = (rloc & 1) ? t1 : t0;
        float a23 = (rloc & 1) ? t3 : t2;
        float lg_me = (rloc & 2) ? a23 : a01;

        // store logits (lanes 0..15 cover rows n0w..n0w+15, coalesced)
        if (lane < 16) ws[OFF_LOGITS + (size_t)b * N_ + n0w + lane] = lg_me;

        // wave max over its 16 rows
        float mt = fmaxf(fmaxf(lp[0], lp[1]), fmaxf(lp[2], lp[3]));
        mt = fmaxf(mt, __shfl_xor(mt, 16, 64));
        mt = fmaxf(mt, __shfl_xor(mt, 32, 64));

        // wave-private online softmax update
        const float mn = fmaxf(m_w, mt);
        const float alpha = __expf(m_w - mn);
        const float wme = __expf(lg_me - mn);
        float s = wme;
#pragma unroll
        for (int m = 1; m <= 8; m <<= 1) s += __shfl_xor(s, m, 64);
        l_w = l_w * alpha + s;
        m_w = mn;

        if (alpha != 1.0f) {
#pragma unroll
            for (int j = 0; j < 32; ++j) o32[j] *= alpha;
        }
        // o-update from the registers we already hold (f16 -> f32 cvt)
#pragma unroll
        for (int kk = 0; kk < 4; ++kk) {
#pragma unroll
            for (int j = 0; j < 8; ++j)
                o32[kk * 8 + j] += wme * (float)af[kk][j];
        }
    }

    // ---- intra-wave o reduction over the 16 rows (lanes, bits 0-3)
#pragma unroll
    for (int m = 1; m <= 8; m <<= 1) {
#pragma unroll
        for (int j = 0; j < 32; ++j) o32[j] += __shfl_xor(o32[j], m, 64);
    }
    // every lane in group grp now holds o for cols {kk*32 + grp*8 + jj}
    // each lane writes 2 of the 32 values
    {
        const int j0 = rloc * 2;
#pragma unroll
        for (int u = 0; u < 2; ++u) {
            const int j = j0 + u;
            obuf[w][(j >> 3) * 32 + colb + (j & 7)] = o32[j];
        }
        if (lane == 0) { mbuf[w] = m_w; lbuf[w] = l_w; }
    }
    __syncthreads();

    // ---- merge 4 wave partials -> chunk partial
    float* part = ws + OFF_PART + ((size_t)b * CCH + c) * 132;
    if (tid < P_) {
        const float mb = fmaxf(fmaxf(mbuf[0], mbuf[1]), fmaxf(mbuf[2], mbuf[3]));
        float lb = 0.f, oh = 0.f;
#pragma unroll
        for (int ww = 0; ww < 4; ++ww) {
            const float e = __expf(mbuf[ww] - mb);
            lb += e * lbuf[ww];
            oh += e * obuf[ww][tid];
        }
        part[2 + tid] = oh;
        if (tid == 0) { part[0] = mb; part[1] = lb; }
    }
}

// ---------- K2: combine chunk partials -> att; w = exp(logit-m)/l ----------
// R6: k2a+k2b fused. Every thread redundantly recomputes (m,l) from the 8
// chunk partials (16 broadcast loads + 8 exp — free); no barrier, no OFF_FIN
// round-trip. grid (4, B): blockIdx.x=quarter of the N range; quarter 0 also
// writes att.
__global__ __launch_bounds__(256) void k2_final(
    const float* __restrict__ ws, float* __restrict__ out)
{
    const int c4 = blockIdx.x;          // 0..3, quarter of the row
    const int b  = blockIdx.y;
    const int tid = threadIdx.x;
    const float* part = ws + OFF_PART + (size_t)b * CCH * 132;

    float m = -1e30f;
#pragma unroll
    for (int cc = 0; cc < CCH; ++cc) m = fmaxf(m, part[cc * 132]);
    float l = 0.f;
#pragma unroll
    for (int cc = 0; cc < CCH; ++cc)
        l += __expf(part[cc * 132] - m) * part[cc * 132 + 1];
    const float il = 1.0f / l;

    if (c4 == 0 && tid < P_) {
        float a = 0.f;
#pragma unroll
        for (int cc = 0; cc < CCH; ++cc)
            a += __expf(part[cc * 132] - m) * part[cc * 132 + 2 + tid];
        out[(size_t)b * H_ + tid] = a * il;
    }

    const float4* lg4 = (const float4*)(ws + OFF_LOGITS + (size_t)b * N_ + c4 * 1024);
    float4* w4 = (float4*)(out + B_ * H_ + (size_t)b * N_ + c4 * 1024);
    float4 g = lg4[tid];
    float4 r;
    r.x = __expf(g.x - m) * il;
    r.y = __expf(g.y - m) * il;
    r.z = __expf(g.z - m) * il;
    r.w = __expf(g.w - m) * il;
    w4[tid] = r;
}

extern "C" void kernel_launch(void* const* d_in, const int* in_sizes, int n_in,
                              void* d_out, int out_size, void* d_ws, size_t ws_size,
                              hipStream_t stream) {
    const float* v    = (const float*)d_in[0];
    const float* q    = (const float*)d_in[1];
    const float* mask = (const float*)d_in[2];
    const float* Wv   = (const float*)d_in[3];
    const float* bv   = (const float*)d_in[4];
    const float* gv   = (const float*)d_in[5];
    const float* Wq   = (const float*)d_in[6];
    const float* bq   = (const float*)d_in[7];
    const float* gq   = (const float*)d_in[8];
    const float* Wa   = (const float*)d_in[9];
    const float* ba   = (const float*)d_in[10];
    const float* ga   = (const float*)d_in[11];
    float* out = (float*)d_out;
    float* ws  = (float*)d_ws;

    k0_prep<<<1, 1024, 0, stream>>>(Wv, gv, Wq, gq, Wa, ga, ws);
    k1_main<<<dim3(CCH, B_), 256, 0, stream>>>(v, mask, ba, q, Wq, bq, bv, ws);
    k2_final<<<dim3(4, B_), 256, 0, stream>>>(ws, out);
}